// Round 3
// baseline (528.917 us; speedup 1.0000x reference)
//
#include <hip/hip_runtime.h>
#include <math.h>

#define SEQ    4096
#define NFFT   8192
#define DMODEL 1024
#define ORDER  64
#define CT     512
#define MLPT   256

typedef float2 cf;

// LDS swizzle on complex index: XOR bits [3:1] with bits [6:4].
// Conflict-free (8 lanes/bank-quad) for all stage access patterns; preserves
// even pairs (bit 0) and float4 (16 B) alignment.
#define ZI(c) ((c) ^ ((((c) >> 4) & 7) << 1))

__device__ __forceinline__ cf cadd(cf a, cf b) { return make_float2(a.x + b.x, a.y + b.y); }
__device__ __forceinline__ cf csub(cf a, cf b) { return make_float2(a.x - b.x, a.y - b.y); }
__device__ __forceinline__ cf cmul(cf a, cf b) { return make_float2(a.x * b.x - a.y * b.y, a.x * b.y + a.y * b.x); }
__device__ __forceinline__ cf cmulj(cf a, cf b) { return make_float2(a.x * b.x + a.y * b.y, a.y * b.x - a.x * b.y); } // a*conj(b)

#define RT2 0.70710678118654752f
#define C16 0.92387953251128676f
#define S16 0.38268343236508977f

// multiply by (cx, -sy) fwd / (cx, +sy) inv
template<bool INV>
__device__ __forceinline__ cf cmulc(cf a, float cx, float sy) {
    if (!INV) return make_float2(a.x * cx + a.y * sy, a.y * cx - a.x * sy);
    else      return make_float2(a.x * cx - a.y * sy, a.y * cx + a.x * sy);
}
template<bool INV> __device__ __forceinline__ cf tw8_1(cf d) {   // * w8^{±1}
    if (!INV) return make_float2(RT2 * (d.x + d.y), RT2 * (d.y - d.x));
    else      return make_float2(RT2 * (d.x - d.y), RT2 * (d.y + d.x));
}
template<bool INV> __device__ __forceinline__ cf tw8_2(cf d) {   // * (∓i)
    if (!INV) return make_float2(d.y, -d.x);
    else      return make_float2(-d.y, d.x);
}
template<bool INV> __device__ __forceinline__ cf tw8_3(cf d) {   // * w8^{±3}
    if (!INV) return make_float2(RT2 * (d.y - d.x), -RT2 * (d.x + d.y));
    else      return make_float2(-RT2 * (d.x + d.y), RT2 * (d.x - d.y));
}

template<bool INV>
__device__ __forceinline__ void dft4(cf& x0, cf& x1, cf& x2, cf& x3) {
    cf A = cadd(x0, x2), B = csub(x0, x2);
    cf C = cadd(x1, x3), D = csub(x1, x3);
    x0 = cadd(A, C); x2 = csub(A, C);
    if (!INV) { x1 = make_float2(B.x + D.y, B.y - D.x); x3 = make_float2(B.x - D.y, B.y + D.x); }
    else      { x1 = make_float2(B.x - D.y, B.y + D.x); x3 = make_float2(B.x + D.y, B.y - D.x); }
}

// y_k = sum_m v_m w8^{∓km}, natural order in/out
template<bool INV>
__device__ __forceinline__ void dft8(cf v[8]) {
    cf s0 = cadd(v[0], v[4]), s1 = cadd(v[1], v[5]), s2 = cadd(v[2], v[6]), s3 = cadd(v[3], v[7]);
    cf d0 = csub(v[0], v[4]), d1 = csub(v[1], v[5]), d2 = csub(v[2], v[6]), d3 = csub(v[3], v[7]);
    cf t1 = tw8_1<INV>(d1), t2 = tw8_2<INV>(d2), t3 = tw8_3<INV>(d3);
    dft4<INV>(s0, s1, s2, s3);
    dft4<INV>(d0, t1, t2, t3);
    v[0] = s0; v[2] = s1; v[4] = s2; v[6] = s3;
    v[1] = d0; v[3] = t1; v[5] = t2; v[7] = t3;
}

template<bool INV>
__device__ __forceinline__ void dft16(cf v[16]) {
    cf s[8], t[8];
    #pragma unroll
    for (int m = 0; m < 8; m++) { s[m] = cadd(v[m], v[m + 8]); t[m] = csub(v[m], v[m + 8]); }
    t[1] = cmulc<INV>(t[1], C16, S16);
    t[2] = tw8_1<INV>(t[2]);
    t[3] = cmulc<INV>(t[3], S16, C16);
    t[4] = tw8_2<INV>(t[4]);
    t[5] = cmulc<INV>(t[5], -S16, C16);
    t[6] = tw8_3<INV>(t[6]);
    t[7] = cmulc<INV>(t[7], -C16, S16);
    dft8<INV>(s); dft8<INV>(t);
    #pragma unroll
    for (int k = 0; k < 8; k++) { v[2 * k] = s[k]; v[2 * k + 1] = t[k]; }
}

// thread -> (block base, pair start j0) for stride L
template<int L>
__device__ __forceinline__ void stage_map(int t, int& j0, int& base) {
    if (L == 1024)     { j0 = 2 * t;        base = 0; }
    else if (L == 128) { j0 = 2 * (t & 63); base = (t >> 6) << 10; }
    else               { j0 = 2 * (t & 7);  base = (t >> 3) << 7; }
}

// Fwd radix-8 DIF stage, stride L, twiddle LUT stride S = 8192/(8L).
// FIRST: inputs at k>=4 are implicitly zero (zero-padded signal).
template<int L, int S, bool FIRST>
__device__ __forceinline__ void stage_fwd(float2* z, const cf* __restrict__ tw) {
    int t = threadIdx.x, j0, base;
    stage_map<L>(t, j0, base);
    int c0 = base + j0;
    cf a[8], b[8];
    #pragma unroll
    for (int k = 0; k < 8; k++) {
        if (FIRST && k >= 4) { a[k] = make_float2(0.f, 0.f); b[k] = a[k]; }
        else {
            float4 p = *(const float4*)&z[ZI(c0 + k * L)];
            a[k] = make_float2(p.x, p.y); b[k] = make_float2(p.z, p.w);
        }
    }
    dft8<false>(a); dft8<false>(b);
    cf wA = tw[S * j0], wB = tw[S * j0 + S];
    cf cA = wA, cB = wB;
    #pragma unroll
    for (int k = 1; k < 8; k++) {
        a[k] = cmul(a[k], cA); b[k] = cmul(b[k], cB);
        if (k < 7) { cA = cmul(cA, wA); cB = cmul(cB, wB); }
    }
    #pragma unroll
    for (int k = 0; k < 8; k++)
        *(float4*)&z[ZI(c0 + k * L)] = make_float4(a[k].x, a[k].y, b[k].x, b[k].y);
    __syncthreads();
}

// Inverse stage: de-twiddle (conj) then inverse DFT-8, same positions.
template<int L, int S>
__device__ __forceinline__ void stage_inv(float2* z, const cf* __restrict__ tw) {
    int t = threadIdx.x, j0, base;
    stage_map<L>(t, j0, base);
    int c0 = base + j0;
    cf a[8], b[8];
    #pragma unroll
    for (int k = 0; k < 8; k++) {
        float4 p = *(const float4*)&z[ZI(c0 + k * L)];
        a[k] = make_float2(p.x, p.y); b[k] = make_float2(p.z, p.w);
    }
    cf wA = tw[S * j0], wB = tw[S * j0 + S];
    cf cA = wA, cB = wB;
    #pragma unroll
    for (int k = 1; k < 8; k++) {
        a[k] = cmulj(a[k], cA); b[k] = cmulj(b[k], cB);
        if (k < 7) { cA = cmul(cA, wA); cB = cmul(cB, wB); }
    }
    dft8<true>(a); dft8<true>(b);
    #pragma unroll
    for (int k = 0; k < 8; k++)
        *(float4*)&z[ZI(c0 + k * L)] = make_float4(a[k].x, a[k].y, b[k].x, b[k].y);
    __syncthreads();
}

// ---------------------------------------------------------------------------
__global__ void tw_init_kernel(cf* __restrict__ tw) {
    int j = blockIdx.x * blockDim.x + threadIdx.x;
    if (j < NFFT) {
        double ang = (2.0 * M_PI / (double)NFFT) * (double)j;
        tw[j] = make_float2((float)cos(ang), (float)(-sin(ang)));
    }
}

// ---------------------------------------------------------------------------
__global__ void mlp_kernel(const float* __restrict__ W1, const float* __restrict__ b1,
                           const float* __restrict__ W2, const float* __restrict__ b2,
                           const float* __restrict__ W3, const float* __restrict__ b3,
                           const float* __restrict__ freq, float* __restrict__ Ht) {
    int o = threadIdx.x & 63;
    int p = threadIdx.x >> 6;
    int l = blockIdx.x * 4 + p;
    __shared__ float hs[4][ORDER];

    float t   = (float)l / 4095.0f;
    float ang = 1e-4f * (float)(2.0 * M_PI) * (float)l / 4096.0f;
    float z0 = t, z1 = cosf(ang), z2 = -sinf(ang);
    float fo = freq[o];

    float a = z0 * W1[o] + z1 * W1[ORDER + o] + z2 * W1[2 * ORDER + o] + b1[o];
    hs[p][o] = sinf(fo * a);
    __syncthreads();

    a = b2[o];
    #pragma unroll
    for (int i = 0; i < ORDER; i++) a += hs[p][i] * W2[i * ORDER + o];
    float h2 = sinf(fo * a);
    __syncthreads();
    hs[p][o] = h2;
    __syncthreads();

    a = b3[o];
    #pragma unroll
    for (int i = 0; i < ORDER; i++) a += hs[p][i] * W3[i * ORDER + o];
    Ht[o * SEQ + l] = sinf(fo * a);
}

// ---------------------------------------------------------------------------
// kf[d][l] = (Ht^T Wout)[l][d] * exp(-t_l * delta_d)
// grid 256: blockIdx = lt (0..63) | dq<<6 ; 256 threads.
// ---------------------------------------------------------------------------
__global__ void kgen_kernel(const float* __restrict__ Wout, const float* __restrict__ Ht,
                            float* __restrict__ kf) {
    __shared__ float sh[ORDER][ORDER + 1];
    int t  = threadIdx.x;
    int lt = blockIdx.x & 63, dq = blockIdx.x >> 6;
    int l  = t & 63;
    for (int o = t >> 6; o < ORDER; o += 4)
        sh[o][l] = Ht[o * SEQ + lt * 64 + l];
    __syncthreads();

    const float MIN_D = -3.0701134573253944f;   // log(.01)/1.5
    const float MAX_D = -15.350567286626971f;   // log(.01)/0.3
    float tl = (float)(lt * 64 + l) / 4095.0f;
    for (int d = dq * 256 + (t >> 6); d < (dq + 1) * 256; d += 4) {
        float acc = 0.0f;
        #pragma unroll
        for (int o = 0; o < ORDER; o++) acc += sh[o][l] * Wout[o * DMODEL + d];
        float delta = fabsf(MIN_D + (MAX_D - MIN_D) * (float)d / 1023.0f);
        kf[(size_t)d * SEQ + lt * 64 + l] = acc * expf(-tl * delta);
    }
}

// ---------------------------------------------------------------------------
// Filter FFT: Kbr[d][p] = fwd-permuted spectrum * 1/N
// ---------------------------------------------------------------------------
__global__ __launch_bounds__(CT, 4) void kfft_kernel(const float* __restrict__ kf,
                                                     const cf* __restrict__ tw,
                                                     cf* __restrict__ Kbr) {
    int d = blockIdx.x, t = threadIdx.x;
    __shared__ __align__(16) float2 z[NFFT];
    const float2* kf2 = (const float2*)(kf + (size_t)d * SEQ);
    #pragma unroll
    for (int m = 0; m < 4; m++) {
        int s = t + 512 * m;
        float2 v = kf2[s];
        *(float4*)&z[ZI(2 * s)] = make_float4(v.x, 0.f, v.y, 0.f);
    }
    __syncthreads();
    stage_fwd<1024, 1, true>(z, tw);
    stage_fwd<128, 8, false>(z, tw);
    stage_fwd<16, 64, false>(z, tw);

    cf v[16];
    int c0 = 16 * t;
    #pragma unroll
    for (int i = 0; i < 8; i++) {
        float4 p = *(const float4*)&z[ZI(c0 + 2 * i)];
        v[2 * i] = make_float2(p.x, p.y); v[2 * i + 1] = make_float2(p.z, p.w);
    }
    dft16<false>(v);
    const float sc = 1.0f / (float)NFFT;
    float4* K4 = (float4*)(Kbr + (size_t)d * NFFT + c0);
    #pragma unroll
    for (int i = 0; i < 8; i++)
        K4[i] = make_float4(v[2 * i].x * sc, v[2 * i].y * sc,
                            v[2 * i + 1].x * sc, v[2 * i + 1].y * sc);
}

// ---------------------------------------------------------------------------
// Main conv: z = xa + i*xb, fwd FFT, *K (registers), inv FFT, epilogue.
// ---------------------------------------------------------------------------
__global__ __launch_bounds__(CT, 4) void conv_kernel(const float* __restrict__ x,
                                                     const float* __restrict__ bias,
                                                     const cf* __restrict__ Kbr,
                                                     const cf* __restrict__ tw,
                                                     float* __restrict__ out) {
    int wg = blockIdx.x;
    int d = wg & (DMODEL - 1);
    int pair = wg >> 10;
    int t = threadIdx.x;

    const float2* xa2 = (const float2*)(x + ((size_t)(2 * pair) * DMODEL + d) * SEQ);
    const float2* xb2 = (const float2*)(x + ((size_t)(2 * pair + 1) * DMODEL + d) * SEQ);

    __shared__ __align__(16) float2 z[NFFT];

    float2 ra[4], rb[4];
    #pragma unroll
    for (int m = 0; m < 4; m++) {
        int s = t + 512 * m;
        ra[m] = xa2[s]; rb[m] = xb2[s];
        *(float4*)&z[ZI(2 * s)] = make_float4(ra[m].x, rb[m].x, ra[m].y, rb[m].y);
    }
    __syncthreads();

    stage_fwd<1024, 1, true>(z, tw);
    stage_fwd<128, 8, false>(z, tw);
    stage_fwd<16, 64, false>(z, tw);

    // S4 + pointwise + I4, all in registers
    cf v[16];
    int c0 = 16 * t;
    #pragma unroll
    for (int i = 0; i < 8; i++) {
        float4 p = *(const float4*)&z[ZI(c0 + 2 * i)];
        v[2 * i] = make_float2(p.x, p.y); v[2 * i + 1] = make_float2(p.z, p.w);
    }
    dft16<false>(v);
    const float4* K4 = (const float4*)(Kbr + (size_t)d * NFFT + c0);
    #pragma unroll
    for (int i = 0; i < 8; i++) {
        float4 kk = K4[i];
        v[2 * i]     = cmul(v[2 * i],     make_float2(kk.x, kk.y));
        v[2 * i + 1] = cmul(v[2 * i + 1], make_float2(kk.z, kk.w));
    }
    dft16<true>(v);
    #pragma unroll
    for (int i = 0; i < 8; i++)
        *(float4*)&z[ZI(c0 + 2 * i)] = make_float4(v[2 * i].x, v[2 * i].y,
                                                   v[2 * i + 1].x, v[2 * i + 1].y);
    __syncthreads();

    stage_inv<16, 64>(z, tw);
    stage_inv<128, 8>(z, tw);

    // last inverse stage (L=1024) fused with epilogue; outputs only pos<4096
    {
        int j0 = 2 * t;
        cf a[8], b[8];
        #pragma unroll
        for (int k = 0; k < 8; k++) {
            float4 p = *(const float4*)&z[ZI(j0 + k * 1024)];
            a[k] = make_float2(p.x, p.y); b[k] = make_float2(p.z, p.w);
        }
        cf wA = tw[j0], wB = tw[j0 + 1];
        cf cA = wA, cB = wB;
        #pragma unroll
        for (int k = 1; k < 8; k++) {
            a[k] = cmulj(a[k], cA); b[k] = cmulj(b[k], cB);
            if (k < 7) { cA = cmul(cA, wA); cB = cmul(cB, wB); }
        }
        dft8<true>(a); dft8<true>(b);

        float bd = bias[d];
        float2* oa2 = (float2*)(out + ((size_t)(2 * pair) * DMODEL + d) * SEQ);
        float2* ob2 = (float2*)(out + ((size_t)(2 * pair + 1) * DMODEL + d) * SEQ);
        #pragma unroll
        for (int m = 0; m < 4; m++) {
            int s = t + 512 * m;
            oa2[s] = make_float2(a[m].x + bd * ra[m].x, b[m].x + bd * ra[m].y);
            ob2[s] = make_float2(a[m].y + bd * rb[m].x, b[m].y + bd * rb[m].y);
        }
    }
}

// ---------------------------------------------------------------------------
extern "C" void kernel_launch(void* const* d_in, const int* in_sizes, int n_in,
                              void* d_out, int out_size, void* d_ws, size_t ws_size,
                              hipStream_t stream) {
    (void)in_sizes; (void)n_in; (void)out_size; (void)ws_size;
    const float* x    = (const float*)d_in[0];
    const float* bias = (const float*)d_in[1];
    const float* W1   = (const float*)d_in[2];
    const float* b1   = (const float*)d_in[3];
    const float* W2   = (const float*)d_in[4];
    const float* b2   = (const float*)d_in[5];
    const float* W3   = (const float*)d_in[6];
    const float* b3   = (const float*)d_in[7];
    const float* Wout = (const float*)d_in[8];
    const float* freq = (const float*)d_in[9];
    float* out = (float*)d_out;

    // ws floats: Ht[262144] | tw[8192 cf] | kf[4194304] | Kbr[8192*1024 cf]
    float* wsf = (float*)d_ws;
    float* Ht  = wsf;
    cf*    tw  = (cf*)(wsf + 262144);
    float* kf  = wsf + 262144 + 16384;
    cf*    Kbr = (cf*)(wsf + 262144 + 16384 + 4194304);

    hipLaunchKernelGGL(tw_init_kernel, dim3(NFFT / MLPT), dim3(MLPT), 0, stream, tw);
    hipLaunchKernelGGL(mlp_kernel, dim3(SEQ / 4), dim3(MLPT), 0, stream,
                       W1, b1, W2, b2, W3, b3, freq, Ht);
    hipLaunchKernelGGL(kgen_kernel, dim3(256), dim3(MLPT), 0, stream, Wout, Ht, kf);
    hipLaunchKernelGGL(kfft_kernel, dim3(DMODEL), dim3(CT), 0, stream, kf, tw, Kbr);
    hipLaunchKernelGGL(conv_kernel, dim3(DMODEL * 4), dim3(CT), 0, stream,
                       x, bias, Kbr, tw, out);
}

// Round 4
// 342.090 us; speedup vs baseline: 1.5461x; 1.5461x over previous
//
#include <hip/hip_runtime.h>
#include <math.h>

#define SEQ    4096
#define NFFT   8192
#define DMODEL 1024
#define ORDER  64
#define CT     512
#define MLPT   256

typedef float2 cf;

// LDS swizzle on complex index: XOR bits [3:1] with bits [6:4].
// Conflict-free for all stage access patterns; preserves even pairs (bit 0)
// and float4 (16 B) alignment.
#define ZI(c) ((c) ^ ((((c) >> 4) & 7) << 1))

__device__ __forceinline__ cf cadd(cf a, cf b) { return make_float2(a.x + b.x, a.y + b.y); }
__device__ __forceinline__ cf csub(cf a, cf b) { return make_float2(a.x - b.x, a.y - b.y); }
__device__ __forceinline__ cf cmul(cf a, cf b) { return make_float2(a.x * b.x - a.y * b.y, a.x * b.y + a.y * b.x); }
__device__ __forceinline__ cf cmulj(cf a, cf b) { return make_float2(a.x * b.x + a.y * b.y, a.y * b.x - a.x * b.y); } // a*conj(b)

#define RT2 0.70710678118654752f
#define C16 0.92387953251128676f
#define S16 0.38268343236508977f

template<bool INV>
__device__ __forceinline__ cf cmulc(cf a, float cx, float sy) {
    if (!INV) return make_float2(a.x * cx + a.y * sy, a.y * cx - a.x * sy);
    else      return make_float2(a.x * cx - a.y * sy, a.y * cx + a.x * sy);
}
template<bool INV> __device__ __forceinline__ cf tw8_1(cf d) {
    if (!INV) return make_float2(RT2 * (d.x + d.y), RT2 * (d.y - d.x));
    else      return make_float2(RT2 * (d.x - d.y), RT2 * (d.y + d.x));
}
template<bool INV> __device__ __forceinline__ cf tw8_2(cf d) {
    if (!INV) return make_float2(d.y, -d.x);
    else      return make_float2(-d.y, d.x);
}
template<bool INV> __device__ __forceinline__ cf tw8_3(cf d) {
    if (!INV) return make_float2(RT2 * (d.y - d.x), -RT2 * (d.x + d.y));
    else      return make_float2(-RT2 * (d.x + d.y), RT2 * (d.x - d.y));
}

template<bool INV>
__device__ __forceinline__ void dft4(cf& x0, cf& x1, cf& x2, cf& x3) {
    cf A = cadd(x0, x2), B = csub(x0, x2);
    cf C = cadd(x1, x3), D = csub(x1, x3);
    x0 = cadd(A, C); x2 = csub(A, C);
    if (!INV) { x1 = make_float2(B.x + D.y, B.y - D.x); x3 = make_float2(B.x - D.y, B.y + D.x); }
    else      { x1 = make_float2(B.x - D.y, B.y + D.x); x3 = make_float2(B.x + D.y, B.y - D.x); }
}

template<bool INV>
__device__ __forceinline__ void dft8(cf v[8]) {
    cf s0 = cadd(v[0], v[4]), s1 = cadd(v[1], v[5]), s2 = cadd(v[2], v[6]), s3 = cadd(v[3], v[7]);
    cf d0 = csub(v[0], v[4]), d1 = csub(v[1], v[5]), d2 = csub(v[2], v[6]), d3 = csub(v[3], v[7]);
    cf t1 = tw8_1<INV>(d1), t2 = tw8_2<INV>(d2), t3 = tw8_3<INV>(d3);
    dft4<INV>(s0, s1, s2, s3);
    dft4<INV>(d0, t1, t2, t3);
    v[0] = s0; v[2] = s1; v[4] = s2; v[6] = s3;
    v[1] = d0; v[3] = t1; v[5] = t2; v[7] = t3;
}

template<bool INV>
__device__ __forceinline__ void dft16(cf v[16]) {
    cf s[8], t[8];
    #pragma unroll
    for (int m = 0; m < 8; m++) { s[m] = cadd(v[m], v[m + 8]); t[m] = csub(v[m], v[m + 8]); }
    t[1] = cmulc<INV>(t[1], C16, S16);
    t[2] = tw8_1<INV>(t[2]);
    t[3] = cmulc<INV>(t[3], S16, C16);
    t[4] = tw8_2<INV>(t[4]);
    t[5] = cmulc<INV>(t[5], -S16, C16);
    t[6] = tw8_3<INV>(t[6]);
    t[7] = cmulc<INV>(t[7], -C16, S16);
    dft8<INV>(s); dft8<INV>(t);
    #pragma unroll
    for (int k = 0; k < 8; k++) { v[2 * k] = s[k]; v[2 * k + 1] = t[k]; }
}

template<int L>
__device__ __forceinline__ void stage_map(int t, int& j0, int& base) {
    if (L == 1024)     { j0 = 2 * t;        base = 0; }
    else if (L == 128) { j0 = 2 * (t & 63); base = (t >> 6) << 10; }
    else               { j0 = 2 * (t & 7);  base = (t >> 3) << 7; }
}

template<int L, int S, bool FIRST>
__device__ __forceinline__ void stage_fwd(float2* z, const cf* __restrict__ tw) {
    int t = threadIdx.x, j0, base;
    stage_map<L>(t, j0, base);
    int c0 = base + j0;
    cf a[8], b[8];
    #pragma unroll
    for (int k = 0; k < 8; k++) {
        if (FIRST && k >= 4) { a[k] = make_float2(0.f, 0.f); b[k] = a[k]; }
        else {
            float4 p = *(const float4*)&z[ZI(c0 + k * L)];
            a[k] = make_float2(p.x, p.y); b[k] = make_float2(p.z, p.w);
        }
    }
    dft8<false>(a); dft8<false>(b);
    cf wA = tw[S * j0], wB = tw[S * j0 + S];
    cf cA = wA, cB = wB;
    #pragma unroll
    for (int k = 1; k < 8; k++) {
        a[k] = cmul(a[k], cA); b[k] = cmul(b[k], cB);
        if (k < 7) { cA = cmul(cA, wA); cB = cmul(cB, wB); }
    }
    #pragma unroll
    for (int k = 0; k < 8; k++)
        *(float4*)&z[ZI(c0 + k * L)] = make_float4(a[k].x, a[k].y, b[k].x, b[k].y);
    __syncthreads();
}

template<int L, int S>
__device__ __forceinline__ void stage_inv(float2* z, const cf* __restrict__ tw) {
    int t = threadIdx.x, j0, base;
    stage_map<L>(t, j0, base);
    int c0 = base + j0;
    cf a[8], b[8];
    #pragma unroll
    for (int k = 0; k < 8; k++) {
        float4 p = *(const float4*)&z[ZI(c0 + k * L)];
        a[k] = make_float2(p.x, p.y); b[k] = make_float2(p.z, p.w);
    }
    cf wA = tw[S * j0], wB = tw[S * j0 + S];
    cf cA = wA, cB = wB;
    #pragma unroll
    for (int k = 1; k < 8; k++) {
        a[k] = cmulj(a[k], cA); b[k] = cmulj(b[k], cB);
        if (k < 7) { cA = cmul(cA, wA); cB = cmul(cB, wB); }
    }
    dft8<true>(a); dft8<true>(b);
    #pragma unroll
    for (int k = 0; k < 8; k++)
        *(float4*)&z[ZI(c0 + k * L)] = make_float4(a[k].x, a[k].y, b[k].x, b[k].y);
    __syncthreads();
}

// ---------------------------------------------------------------------------
__global__ void tw_init_kernel(cf* __restrict__ tw) {
    int j = blockIdx.x * blockDim.x + threadIdx.x;
    if (j < NFFT) {
        double ang = (2.0 * M_PI / (double)NFFT) * (double)j;
        tw[j] = make_float2((float)cos(ang), (float)(-sin(ang)));
    }
}

// ---------------------------------------------------------------------------
__global__ void mlp_kernel(const float* __restrict__ W1, const float* __restrict__ b1,
                           const float* __restrict__ W2, const float* __restrict__ b2,
                           const float* __restrict__ W3, const float* __restrict__ b3,
                           const float* __restrict__ freq, float* __restrict__ Ht) {
    int o = threadIdx.x & 63;
    int p = threadIdx.x >> 6;
    int l = blockIdx.x * 4 + p;
    __shared__ float hs[4][ORDER];

    float t   = (float)l / 4095.0f;
    float ang = 1e-4f * (float)(2.0 * M_PI) * (float)l / 4096.0f;
    float z0 = t, z1 = cosf(ang), z2 = -sinf(ang);
    float fo = freq[o];

    float a = z0 * W1[o] + z1 * W1[ORDER + o] + z2 * W1[2 * ORDER + o] + b1[o];
    hs[p][o] = sinf(fo * a);
    __syncthreads();

    a = b2[o];
    #pragma unroll
    for (int i = 0; i < ORDER; i++) a += hs[p][i] * W2[i * ORDER + o];
    float h2 = sinf(fo * a);
    __syncthreads();
    hs[p][o] = h2;
    __syncthreads();

    a = b3[o];
    #pragma unroll
    for (int i = 0; i < ORDER; i++) a += hs[p][i] * W3[i * ORDER + o];
    Ht[o * SEQ + l] = sinf(fo * a);
}

// ---------------------------------------------------------------------------
// Filter gen (matmul + modulation, inline) + forward FFT.
// Kbr[d][p] = fwd-permuted spectrum * 1/N.
// ---------------------------------------------------------------------------
__global__ __launch_bounds__(CT, 4) void kfft_kernel(const float* __restrict__ Wout,
                                                     const float* __restrict__ Ht,
                                                     const cf* __restrict__ tw,
                                                     cf* __restrict__ Kbr) {
    int d = blockIdx.x, t = threadIdx.x;
    __shared__ __align__(16) float2 z[NFFT];
    __shared__ float wcol[ORDER];

    if (t < ORDER) wcol[t] = Wout[t * DMODEL + d];
    __syncthreads();

    const float MIN_D = -3.0701134573253944f;   // log(.01)/1.5
    const float MAX_D = -15.350567286626971f;   // log(.01)/0.3
    float delta = fabsf(MIN_D + (MAX_D - MIN_D) * (float)d / 1023.0f);

    const float2* Ht2 = (const float2*)Ht;      // [ORDER][SEQ/2]
    #pragma unroll
    for (int m = 0; m < 4; m++) {
        int s = t + 512 * m;                    // pair index, l = 2s, 2s+1
        float acc0 = 0.f, acc1 = 0.f;
        #pragma unroll
        for (int o = 0; o < ORDER; o++) {
            float2 h = Ht2[o * (SEQ / 2) + s];
            float w = wcol[o];
            acc0 += h.x * w; acc1 += h.y * w;
        }
        float t0 = (float)(2 * s)     / 4095.0f;
        float t1 = (float)(2 * s + 1) / 4095.0f;
        acc0 *= expf(-t0 * delta);
        acc1 *= expf(-t1 * delta);
        *(float4*)&z[ZI(2 * s)] = make_float4(acc0, 0.f, acc1, 0.f);
    }
    __syncthreads();

    stage_fwd<1024, 1, true>(z, tw);
    stage_fwd<128, 8, false>(z, tw);
    stage_fwd<16, 64, false>(z, tw);

    cf v[16];
    int c0 = 16 * t;
    #pragma unroll
    for (int i = 0; i < 8; i++) {
        float4 p = *(const float4*)&z[ZI(c0 + 2 * i)];
        v[2 * i] = make_float2(p.x, p.y); v[2 * i + 1] = make_float2(p.z, p.w);
    }
    dft16<false>(v);
    const float sc = 1.0f / (float)NFFT;
    float4* K4 = (float4*)(Kbr + (size_t)d * NFFT + c0);
    #pragma unroll
    for (int i = 0; i < 8; i++)
        K4[i] = make_float4(v[2 * i].x * sc, v[2 * i].y * sc,
                            v[2 * i + 1].x * sc, v[2 * i + 1].y * sc);
}

// ---------------------------------------------------------------------------
// Main conv: z = xa + i*xb, fwd FFT, *K (registers), inv FFT, epilogue.
// ---------------------------------------------------------------------------
__global__ __launch_bounds__(CT, 4) void conv_kernel(const float* __restrict__ x,
                                                     const float* __restrict__ bias,
                                                     const cf* __restrict__ Kbr,
                                                     const cf* __restrict__ tw,
                                                     float* __restrict__ out) {
    int wg = blockIdx.x;
    int d = wg & (DMODEL - 1);
    int pair = wg >> 10;
    int t = threadIdx.x;

    const float2* xa2 = (const float2*)(x + ((size_t)(2 * pair) * DMODEL + d) * SEQ);
    const float2* xb2 = (const float2*)(x + ((size_t)(2 * pair + 1) * DMODEL + d) * SEQ);

    __shared__ __align__(16) float2 z[NFFT];

    float2 ra[4], rb[4];
    #pragma unroll
    for (int m = 0; m < 4; m++) {
        int s = t + 512 * m;
        ra[m] = xa2[s]; rb[m] = xb2[s];
        *(float4*)&z[ZI(2 * s)] = make_float4(ra[m].x, rb[m].x, ra[m].y, rb[m].y);
    }
    __syncthreads();

    stage_fwd<1024, 1, true>(z, tw);
    stage_fwd<128, 8, false>(z, tw);
    stage_fwd<16, 64, false>(z, tw);

    cf v[16];
    int c0 = 16 * t;
    #pragma unroll
    for (int i = 0; i < 8; i++) {
        float4 p = *(const float4*)&z[ZI(c0 + 2 * i)];
        v[2 * i] = make_float2(p.x, p.y); v[2 * i + 1] = make_float2(p.z, p.w);
    }
    dft16<false>(v);
    const float4* K4 = (const float4*)(Kbr + (size_t)d * NFFT + c0);
    #pragma unroll
    for (int i = 0; i < 8; i++) {
        float4 kk = K4[i];
        v[2 * i]     = cmul(v[2 * i],     make_float2(kk.x, kk.y));
        v[2 * i + 1] = cmul(v[2 * i + 1], make_float2(kk.z, kk.w));
    }
    dft16<true>(v);
    #pragma unroll
    for (int i = 0; i < 8; i++)
        *(float4*)&z[ZI(c0 + 2 * i)] = make_float4(v[2 * i].x, v[2 * i].y,
                                                   v[2 * i + 1].x, v[2 * i + 1].y);
    __syncthreads();

    stage_inv<16, 64>(z, tw);
    stage_inv<128, 8>(z, tw);

    {
        int j0 = 2 * t;
        cf a[8], b[8];
        #pragma unroll
        for (int k = 0; k < 8; k++) {
            float4 p = *(const float4*)&z[ZI(j0 + k * 1024)];
            a[k] = make_float2(p.x, p.y); b[k] = make_float2(p.z, p.w);
        }
        cf wA = tw[j0], wB = tw[j0 + 1];
        cf cA = wA, cB = wB;
        #pragma unroll
        for (int k = 1; k < 8; k++) {
            a[k] = cmulj(a[k], cA); b[k] = cmulj(b[k], cB);
            if (k < 7) { cA = cmul(cA, wA); cB = cmul(cB, wB); }
        }
        dft8<true>(a); dft8<true>(b);

        float bd = bias[d];
        float2* oa2 = (float2*)(out + ((size_t)(2 * pair) * DMODEL + d) * SEQ);
        float2* ob2 = (float2*)(out + ((size_t)(2 * pair + 1) * DMODEL + d) * SEQ);
        #pragma unroll
        for (int m = 0; m < 4; m++) {
            int s = t + 512 * m;
            oa2[s] = make_float2(a[m].x + bd * ra[m].x, b[m].x + bd * ra[m].y);
            ob2[s] = make_float2(a[m].y + bd * rb[m].x, b[m].y + bd * rb[m].y);
        }
    }
}

// ---------------------------------------------------------------------------
extern "C" void kernel_launch(void* const* d_in, const int* in_sizes, int n_in,
                              void* d_out, int out_size, void* d_ws, size_t ws_size,
                              hipStream_t stream) {
    (void)in_sizes; (void)n_in; (void)out_size; (void)ws_size;
    const float* x    = (const float*)d_in[0];
    const float* bias = (const float*)d_in[1];
    const float* W1   = (const float*)d_in[2];
    const float* b1   = (const float*)d_in[3];
    const float* W2   = (const float*)d_in[4];
    const float* b2   = (const float*)d_in[5];
    const float* W3   = (const float*)d_in[6];
    const float* b3   = (const float*)d_in[7];
    const float* Wout = (const float*)d_in[8];
    const float* freq = (const float*)d_in[9];
    float* out = (float*)d_out;

    // ws floats: Ht[262144] | tw[8192 cf] | Kbr[8192*1024 cf]
    float* wsf = (float*)d_ws;
    float* Ht  = wsf;
    cf*    tw  = (cf*)(wsf + 262144);
    cf*    Kbr = (cf*)(wsf + 262144 + 16384);

    hipLaunchKernelGGL(tw_init_kernel, dim3(NFFT / MLPT), dim3(MLPT), 0, stream, tw);
    hipLaunchKernelGGL(mlp_kernel, dim3(SEQ / 4), dim3(MLPT), 0, stream,
                       W1, b1, W2, b2, W3, b3, freq, Ht);
    hipLaunchKernelGGL(kfft_kernel, dim3(DMODEL), dim3(CT), 0, stream,
                       Wout, Ht, tw, Kbr);
    hipLaunchKernelGGL(conv_kernel, dim3(DMODEL * 4), dim3(CT), 0, stream,
                       x, bias, Kbr, tw, out);
}